// Round 3
// baseline (369.082 us; speedup 1.0000x reference)
//
#include <hip/hip_runtime.h>
#include <hip/hip_bf16.h>
#include <stdint.h>

#define NB 4
#define NN 2048
#define NF 128
#define NBLK 256
#define NTHR 512

typedef __attribute__((ext_vector_type(8))) short bf16x8;
typedef __attribute__((ext_vector_type(4))) short short4v;
typedef __attribute__((ext_vector_type(4))) float f32x4;

__device__ __forceinline__ short f2bf(float x) {
  __hip_bfloat16 h = __float2bfloat16(x);
  return *reinterpret_cast<short*>(&h);
}
__device__ __forceinline__ float bf2f(short s) {
  unsigned int u = ((unsigned int)(unsigned short)s) << 16;
  return __uint_as_float(u);
}

__device__ __forceinline__ void gload_lds16(void* lds, const void* g) {
  __builtin_amdgcn_global_load_lds(
      (const __attribute__((address_space(1))) unsigned int*)(uintptr_t)g,
      (__attribute__((address_space(3))) unsigned int*)(uintptr_t)lds,
      16, 0, 0);
}

// device-scope grid barrier; bar[0]=count, bar[32]=generation (separate lines)
__device__ __forceinline__ void gridbar(unsigned* bar, unsigned target) {
  __syncthreads();
  __threadfence();
  if (threadIdx.x == 0) {
    unsigned* cnt = bar;
    unsigned* gen = bar + 32;
    if (atomicAdd(cnt, 1u) == NBLK - 1u) {
      atomicExch(cnt, 0u);
      __threadfence();
      atomicAdd(gen, 1u);
    } else {
      while (atomicAdd(gen, 0u) < target) __builtin_amdgcn_s_sleep(2);
    }
  }
  __syncthreads();
  __threadfence();
}

__global__ void k_init(unsigned* bar) { bar[threadIdx.x] = 0u; }

// ---- fused aggregation + linear layer (device function) ----
// y = A_norm @ h  (BM=32, BN=128, BK=128, 8 waves: 4 col-slices x 2 K-halves),
// 3-buffer counted-vmcnt pipeline; then z = y@W + bias (hi/lo bf16 split),
// relu?, + resid; writes f32 out (+ bf16 transposed for next layer).
template <bool LAST>
__device__ __forceinline__ void agg_layer(char* smem, int bid0, int tid,
                                          const short* __restrict__ An,
                                          const short* __restrict__ hT,
                                          const float* __restrict__ resid,
                                          const short* __restrict__ wT,
                                          const float* __restrict__ bias,
                                          float* __restrict__ outF,
                                          short* __restrict__ outT) {
  const int bid = (bid0 & 7) * 32 + (bid0 >> 3);   // XCD-chunked swizzle
  const int b = bid >> 6;
  const int i0 = (bid & 63) << 5;
  const int w = tid >> 6, lane = tid & 63;
  const int lo = lane & 15, hi = lane >> 4;
  const int kg = w >> 2, wc = w & 3;

  // stage-2 W fragments (L2-hot): B[k=f][n=o] from wT[o][f]
  bf16x8 wfrag[4];
#pragma unroll
  for (int ks = 0; ks < 4; ++ks)
    wfrag[ks] = *(const bf16x8*)(wT + (16 * w + lo) * NF + ks * 32 + hi * 8);

  // staging sources (pre-swizzled 16B chunk within each 256 B tile row)
  const int rA = tid >> 4, cA = tid & 15;
  const short* Asrc = An + (size_t)(b * NN + i0 + rA) * NN + ((cA ^ (rA & 7)) * 8);
  const short* Hsrc[4];
#pragma unroll
  for (int p = 0; p < 4; ++p) {
    const int c = tid + 512 * p;
    const int f = c >> 4, ch = c & 15;
    Hsrc[p] = hT + (size_t)(b * NF + f) * NN + ((ch ^ (f & 7)) * 8);
  }

  // fragment ds_read offsets (swizzled, relative to buffer base)
  int offA[2][2], offH[2][2];
#pragma unroll
  for (int mm = 0; mm < 2; ++mm)
#pragma unroll
    for (int ks = 0; ks < 2; ++ks) {
      const int r = 16 * mm + lo;
      const int ck = kg * 8 + ks * 4 + hi;
      offA[mm][ks] = r * 256 + ((ck ^ (r & 7)) << 4);
    }
#pragma unroll
  for (int nn = 0; nn < 2; ++nn)
#pragma unroll
    for (int ks = 0; ks < 2; ++ks) {
      const int f = 32 * wc + 16 * nn + lo;
      const int ck = kg * 8 + ks * 4 + hi;
      offH[nn][ks] = 8192 + f * 256 + ((ck ^ (f & 7)) << 4);
    }

  f32x4 acc[2][2] = {};

#define STAGE_T(t_, base_)                                              \
  do {                                                                  \
    const int koff_ = (t_) * 128;                                       \
    char* nb_ = (base_);                                                \
    gload_lds16(nb_ + tid * 16, Asrc + koff_);                          \
    _Pragma("unroll")                                                   \
    for (int p_ = 0; p_ < 4; ++p_)                                      \
      gload_lds16(nb_ + 8192 + (tid + 512 * p_) * 16, Hsrc[p_] + koff_);\
  } while (0)

  STAGE_T(0, smem);
  STAGE_T(1, smem + 40960);

  const int NT = NN / 128;               // 16 supersteps
  for (int t = 0; t < NT; ++t) {
    asm volatile("s_waitcnt lgkmcnt(0)" ::: "memory");   // my t-1 ds_reads done
    __builtin_amdgcn_s_barrier();                         // everyone done reading t-1
    if (t + 2 < NT) STAGE_T(t + 2, smem + 40960 * ((t + 2) % 3));
    if (t + 2 < NT)      asm volatile("s_waitcnt vmcnt(10)" ::: "memory");
    else if (t + 1 < NT) asm volatile("s_waitcnt vmcnt(5)" ::: "memory");
    else                 asm volatile("s_waitcnt vmcnt(0)" ::: "memory");
    __builtin_amdgcn_s_barrier();                         // tile t fully in LDS
    const char* buf = smem + 40960 * (t % 3);
    bf16x8 af[2][2], hf[2][2];
#pragma unroll
    for (int mm = 0; mm < 2; ++mm)
#pragma unroll
      for (int ks = 0; ks < 2; ++ks)
        af[mm][ks] = *(const bf16x8*)(buf + offA[mm][ks]);
#pragma unroll
    for (int nn = 0; nn < 2; ++nn)
#pragma unroll
      for (int ks = 0; ks < 2; ++ks)
        hf[nn][ks] = *(const bf16x8*)(buf + offH[nn][ks]);
#pragma unroll
    for (int ks = 0; ks < 2; ++ks)
#pragma unroll
      for (int mm = 0; mm < 2; ++mm)
#pragma unroll
        for (int nn = 0; nn < 2; ++nn)
          acc[mm][nn] = __builtin_amdgcn_mfma_f32_16x16x32_bf16(
              af[mm][ks], hf[nn][ks], acc[mm][nn], 0, 0, 0);
  }
#undef STAGE_T
  __syncthreads();

  // ---- exchange: sum K-half partials, split y into bf16 hi+lo ----
  float* yp = (float*)smem;              // [2][32][128] f32 = 32 KB
#pragma unroll
  for (int mm = 0; mm < 2; ++mm)
#pragma unroll
    for (int nn = 0; nn < 2; ++nn) {
      const int f = 32 * wc + 16 * nn + lo;
      const int ib = 16 * mm + hi * 4;
#pragma unroll
      for (int r = 0; r < 4; ++r)
        yp[kg * 4096 + (ib + r) * 128 + f] = acc[mm][nn][r];
    }
  __syncthreads();
  {
    const int ii = tid >> 4;             // 0..31
    const int fc = tid & 15;             // 16B chunk
    const float4 s0 = *(const float4*)(yp + ii * 128 + fc * 8);
    const float4 s1 = *(const float4*)(yp + ii * 128 + fc * 8 + 4);
    const float4 t0 = *(const float4*)(yp + 4096 + ii * 128 + fc * 8);
    const float4 t1 = *(const float4*)(yp + 4096 + ii * 128 + fc * 8 + 4);
    float v[8] = {s0.x + t0.x, s0.y + t0.y, s0.z + t0.z, s0.w + t0.w,
                  s1.x + t1.x, s1.y + t1.y, s1.z + t1.z, s1.w + t1.w};
    bf16x8 vh, vl;
#pragma unroll
    for (int q = 0; q < 8; ++q) {
      vh[q] = f2bf(v[q]);
      vl[q] = f2bf(v[q] - bf2f(vh[q]));
    }
    const int ch = fc ^ (ii & 7);
    *(bf16x8*)(smem + 32768 + ii * 256 + ch * 16) = vh;
    *(bf16x8*)(smem + 40960 + ii * 256 + ch * 16) = vl;
  }
  __syncthreads();

  // ---- stage 2: z = y @ W ; wave w owns o-cols [16w, 16w+16) ----
  f32x4 acc2[2] = {};
#pragma unroll
  for (int ks = 0; ks < 4; ++ks) {
#pragma unroll
    for (int mm = 0; mm < 2; ++mm) {
      const int r = 16 * mm + lo;
      const int ck = (ks * 4 + hi) ^ (r & 7);
      const bf16x8 ahi = *(const bf16x8*)(smem + 32768 + r * 256 + (ck << 4));
      const bf16x8 alo = *(const bf16x8*)(smem + 40960 + r * 256 + (ck << 4));
      acc2[mm] = __builtin_amdgcn_mfma_f32_16x16x32_bf16(ahi, wfrag[ks], acc2[mm], 0, 0, 0);
      acc2[mm] = __builtin_amdgcn_mfma_f32_16x16x32_bf16(alo, wfrag[ks], acc2[mm], 0, 0, 0);
    }
  }

  // ---- epilogue: bias, relu?, residual; write f32 (+ bf16 transposed) ----
  const int o = 16 * w + lo;
  const float bi = bias[o];
#pragma unroll
  for (int mm = 0; mm < 2; ++mm) {
    const int ib = i0 + 16 * mm + hi * 4;
    float zr[4];
#pragma unroll
    for (int r = 0; r < 4; ++r) {
      float z = acc2[mm][r] + bi;
      if (!LAST) z = fmaxf(z, 0.0f);
      const size_t idx = (size_t)(b * NN + ib + r) * NF + o;
      zr[r] = z + resid[idx];
      outF[idx] = zr[r];
    }
    if (!LAST) {
      short4v v;
#pragma unroll
      for (int r = 0; r < 4; ++r) v[r] = f2bf(zr[r]);
      *(short4v*)(outT + (size_t)(b * NF + o) * NN + ib) = v;
    }
  }
}

// ---------------- the fused mega-kernel ----------------
__global__ __launch_bounds__(512, 2) void k_fused(
    const float* __restrict__ x, const float* __restrict__ adj,
    const float* __restrict__ W1, const float* __restrict__ b1,
    const float* __restrict__ W2, const float* __restrict__ b2,
    const float* __restrict__ W3, const float* __restrict__ b3,
    float* __restrict__ out, float* __restrict__ dinv, short* __restrict__ wt,
    short* __restrict__ hT0, short* __restrict__ hT1, short* __restrict__ hT2,
    float* __restrict__ h1, float* __restrict__ h2, short* __restrict__ An,
    unsigned* bar) {
  __shared__ __align__(16) char smem[122880];
  const int bid = blockIdx.x;
  const int tid = threadIdx.x;

  // ---- phase A: degrees (all blocks) + xT (blocks 0..63) + wT (64..66) ----
  {
    const int r0 = bid * 32;
    const int rsub = tid >> 4, cg = tid & 15;
    const float* row = adj + (size_t)(r0 + rsub) * NN + cg * 4;
    float s = 0.f;
#pragma unroll 8
    for (int it = 0; it < 32; ++it) {
      const float4 v = *(const float4*)(row + it * 64);
      s += v.x + v.y + v.z + v.w;
    }
    s += __shfl_xor(s, 1); s += __shfl_xor(s, 2);
    s += __shfl_xor(s, 4); s += __shfl_xor(s, 8);
    if (cg == 0) dinv[r0 + rsub] = rsqrtf(s + 1e-6f);
  }
  if (bid < 64) {
    // transpose one [128 j][128 f] tile of x into hT0[b][f][j] bf16
    short* tile = (short*)smem;          // 128*129 shorts = 33 KB
    const int b = bid >> 4;
    const int j0 = (bid & 15) << 7;
#pragma unroll
    for (int r = 0; r < 4; ++r) {
      const int j = 32 * r + (tid >> 4);
      const int f0 = (tid & 15) * 8;
      const float4* p = (const float4*)(x + ((size_t)(b * NN + j0 + j)) * NF + f0);
      const float4 a0 = p[0], a1 = p[1];
      short* t = tile + j * 129 + f0;
      t[0] = f2bf(a0.x); t[1] = f2bf(a0.y); t[2] = f2bf(a0.z); t[3] = f2bf(a0.w);
      t[4] = f2bf(a1.x); t[5] = f2bf(a1.y); t[6] = f2bf(a1.z); t[7] = f2bf(a1.w);
    }
    __syncthreads();
#pragma unroll
    for (int r = 0; r < 4; ++r) {
      const int f = 32 * r + (tid >> 4);
      const int jc = tid & 15;
      bf16x8 v;
#pragma unroll
      for (int q = 0; q < 8; ++q) v[q] = tile[(jc * 8 + q) * 129 + f];
      *(bf16x8*)(hT0 + ((size_t)(b * NF + f)) * NN + j0 + jc * 8) = v;
    }
  } else if (bid < 67) {
    const int wl = bid - 64;
    const float* W = (wl == 0) ? W1 : (wl == 1) ? W2 : W3;
#pragma unroll 4
    for (int r = 0; r < 32; ++r) {
      const int e = r * 512 + tid;
      wt[wl * 16384 + e] = f2bf(W[(e & 127) * NF + (e >> 7)]);  // wt[o][f]=W[f][o]
    }
  }
  gridbar(bar, 1);

  // ---- phase B: A_norm (bf16) ----
  for (int it = 0; it < 16; ++it) {
    const size_t gid = (size_t)it * (NBLK * NTHR) + (size_t)bid * NTHR + tid;
    const size_t e0 = gid * 8;
    const int b = (int)(e0 >> 22);
    const int rem = (int)(e0 & 0x3FFFFF);
    const int i = rem >> 11;
    const int j = rem & 2047;
    const float di = dinv[b * NN + i];
    const float4* pj = (const float4*)(dinv + b * NN + j);
    const float4 d0 = pj[0], d1 = pj[1];
    const float4* pa = (const float4*)(adj + e0);
    const float4 a0 = pa[0], a1 = pa[1];
    bf16x8 o;
    o[0] = f2bf(a0.x * di * d0.x);
    o[1] = f2bf(a0.y * di * d0.y);
    o[2] = f2bf(a0.z * di * d0.z);
    o[3] = f2bf(a0.w * di * d0.w);
    o[4] = f2bf(a1.x * di * d1.x);
    o[5] = f2bf(a1.y * di * d1.y);
    o[6] = f2bf(a1.z * di * d1.z);
    o[7] = f2bf(a1.w * di * d1.w);
    *(bf16x8*)(An + e0) = o;
  }
  gridbar(bar, 2);

  // ---- phases C/D/E: three fused GCN layers ----
  agg_layer<false>(smem, bid, tid, An, hT0, x,  wt,         b1, h1,  hT1);
  gridbar(bar, 3);
  agg_layer<false>(smem, bid, tid, An, hT1, h1, wt + 16384, b2, h2,  hT2);
  gridbar(bar, 4);
  agg_layer<true >(smem, bid, tid, An, hT2, h2, wt + 32768, b3, out, nullptr);
}

extern "C" void kernel_launch(void* const* d_in, const int* in_sizes, int n_in,
                              void* d_out, int out_size, void* d_ws, size_t ws_size,
                              hipStream_t stream) {
  const float* x   = (const float*)d_in[0];
  const float* adj = (const float*)d_in[1];
  const float* W1  = (const float*)d_in[2];
  const float* b1  = (const float*)d_in[3];
  const float* W2  = (const float*)d_in[4];
  const float* b2  = (const float*)d_in[5];
  const float* W3  = (const float*)d_in[6];
  const float* b3  = (const float*)d_in[7];
  float* out = (float*)d_out;
  char* ws = (char*)d_ws;

  // workspace layout (bytes)
  float* dinv = (float*)(ws + 0);              // 32 KB
  short* wt   = (short*)(ws + 32768);          // 3 * 32 KB
  short* hT0  = (short*)(ws + 131072);         // 2 MB
  short* hT1  = (short*)(ws + 2228224);        // 2 MB
  short* hT2  = (short*)(ws + 4325376);        // 2 MB
  float* h1   = (float*)(ws + 6422528);        // 4 MB
  float* h2   = (float*)(ws + 10616832);       // 4 MB
  short* An   = (short*)(ws + 14811136);       // 32 MB
  unsigned* bar = (unsigned*)(ws + 48365568);  // 2 cachelines

  k_init<<<1, 64, 0, stream>>>(bar);
  k_fused<<<NBLK, NTHR, 0, stream>>>(x, adj, W1, b1, W2, b2, W3, b3,
                                     out, dinv, wt, hT0, hT1, hT2, h1, h2, An, bar);
}

// Round 4
// 80.499 us; speedup vs baseline: 4.5849x; 4.5849x over previous
//
#include <hip/hip_runtime.h>
#include <hip/hip_bf16.h>
#include <stdint.h>

#define NB 4
#define NN 2048
#define NF 128

typedef __attribute__((ext_vector_type(8))) short bf16x8;
typedef __attribute__((ext_vector_type(4))) short short4v;
typedef __attribute__((ext_vector_type(4))) float f32x4;

__device__ __forceinline__ short f2bf(float x) {
  __hip_bfloat16 h = __float2bfloat16(x);
  return *reinterpret_cast<short*>(&h);
}
__device__ __forceinline__ float bf2f(short s) {
  unsigned int u = ((unsigned int)(unsigned short)s) << 16;
  return __uint_as_float(u);
}

__device__ __forceinline__ void gload_lds16(void* lds, const void* g) {
  __builtin_amdgcn_global_load_lds(
      (const __attribute__((address_space(1))) unsigned int*)(uintptr_t)g,
      (__attribute__((address_space(3))) unsigned int*)(uintptr_t)lds,
      16, 0, 0);
}

// ---------------- Kernel 1: prep — row degree -> dinv, and Ab = bf16(adj) ----------------
// One block per row: 64 MB read + 32 MB write, single pass over adj.
__global__ __launch_bounds__(256) void k_prep(const float* __restrict__ adj,
                                              float* __restrict__ dinv,
                                              short* __restrict__ Ab) {
  const int row = blockIdx.x;          // 0 .. NB*NN-1
  const int tid = threadIdx.x;
  const float* src = adj + (size_t)row * NN + tid * 8;
  const float4 v0 = *(const float4*)(src);
  const float4 v1 = *(const float4*)(src + 4);
  bf16x8 o;
  o[0] = f2bf(v0.x); o[1] = f2bf(v0.y); o[2] = f2bf(v0.z); o[3] = f2bf(v0.w);
  o[4] = f2bf(v1.x); o[5] = f2bf(v1.y); o[6] = f2bf(v1.z); o[7] = f2bf(v1.w);
  *(bf16x8*)(Ab + (size_t)row * NN + tid * 8) = o;
  float s = v0.x + v0.y + v0.z + v0.w + v1.x + v1.y + v1.z + v1.w;
  s += __shfl_xor(s, 1);  s += __shfl_xor(s, 2);  s += __shfl_xor(s, 4);
  s += __shfl_xor(s, 8);  s += __shfl_xor(s, 16); s += __shfl_xor(s, 32);
  __shared__ float red[4];
  const int w = tid >> 6, lane = tid & 63;
  if (lane == 0) red[w] = s;
  __syncthreads();
  if (tid == 0) {
    const float d = red[0] + red[1] + red[2] + red[3];
    dinv[row] = rsqrtf(d + 1e-6f);
  }
}

// ---------------- Kernel 2: misc — hT0 = bf16((x*dinv_j)^T) (blocks 0..63), wt (64..66) ----
__global__ __launch_bounds__(256) void k_misc(const float* __restrict__ x,
                                              const float* __restrict__ W1,
                                              const float* __restrict__ W2,
                                              const float* __restrict__ W3,
                                              const float* __restrict__ dinv,
                                              short* __restrict__ xT,
                                              short* __restrict__ wt) {
  const int bid = blockIdx.x;
  const int tid = threadIdx.x;
  if (bid < 64) {
    // transpose one [128 j][128 f] tile of x (scaled by dinv[j]) into xT[b][f][j] bf16
    const int b = bid >> 4;
    const int j0 = (bid & 15) << 7;
    __shared__ short tile[128 * 129];   // +1 short pad: column reads ~conflict-free
#pragma unroll
    for (int r = 0; r < 8; ++r) {
      const int j = 16 * r + (tid >> 4);
      const int f0 = (tid & 15) * 8;
      const float sc = dinv[b * NN + j0 + j];
      const float4* p = (const float4*)(x + ((size_t)(b * NN + j0 + j)) * NF + f0);
      const float4 a0 = p[0], a1 = p[1];
      short* t = tile + j * 129 + f0;
      t[0] = f2bf(a0.x * sc); t[1] = f2bf(a0.y * sc);
      t[2] = f2bf(a0.z * sc); t[3] = f2bf(a0.w * sc);
      t[4] = f2bf(a1.x * sc); t[5] = f2bf(a1.y * sc);
      t[6] = f2bf(a1.z * sc); t[7] = f2bf(a1.w * sc);
    }
    __syncthreads();
#pragma unroll
    for (int r = 0; r < 8; ++r) {
      const int f = 16 * r + (tid >> 4);
      const int jc = tid & 15;
      bf16x8 v;
#pragma unroll
      for (int q = 0; q < 8; ++q) v[q] = tile[(jc * 8 + q) * 129 + f];
      *(bf16x8*)(xT + ((size_t)(b * NF + f)) * NN + j0 + jc * 8) = v;
    }
  } else {
    const int wl = bid - 64;
    const float* W = (wl == 0) ? W1 : (wl == 1) ? W2 : W3;
#pragma unroll 4
    for (int r = 0; r < 64; ++r) {
      const int e = r * 256 + tid;
      const int o = e >> 7, f = e & 127;
      wt[wl * 16384 + e] = f2bf(W[f * NF + o]);   // wt[o][f] = W[f][o]
    }
  }
}

// ---------------- Kernel 3: fused layer ----------------
// y = A_raw @ h_scaled  (BM=32, BN=128, BK=128, 8 waves: 4 col-slices x 2 K-halves)
// then z = dinv_i*(y @ W) + bias (stage-2 MFMA, y split hi/lo bf16), relu?, + resid.
// Writes h_next f32 and (unless LAST) hT_next = bf16(dinv_i * h_next)^T.
template <bool LAST>
__global__ __launch_bounds__(512) void k_agg2(const short* __restrict__ Ab,
                                              const float* __restrict__ dinv,
                                              const short* __restrict__ hT,
                                              const float* __restrict__ resid,
                                              const short* __restrict__ wT,
                                              const float* __restrict__ bias,
                                              float* __restrict__ outF,
                                              short* __restrict__ outT) {
  const int bid0 = blockIdx.x;
  const int bid = (bid0 & 7) * 32 + (bid0 >> 3);   // XCD-chunked swizzle (256 = 8*32)
  const int b = bid >> 6;
  const int i0 = (bid & 63) << 5;
  const int tid = threadIdx.x;
  const int w = tid >> 6, lane = tid & 63;
  const int lo = lane & 15, hi = lane >> 4;
  const int kg = w >> 2, wc = w & 3;

  __shared__ __align__(16) char lds[2][40960];   // per buf: A 32x128 (8K) + H 128x128 (32K)

  // stage-2 W fragments, issued early (L2-hot 32 KB): B[k=f][n=o] from wT[o][f]
  bf16x8 wfrag[4];
#pragma unroll
  for (int ks = 0; ks < 4; ++ks)
    wfrag[ks] = *(const bf16x8*)(wT + (16 * w + lo) * NF + ks * 32 + hi * 8);

  // staging sources (pre-swizzled 16B chunk within each 256 B tile row)
  const int rA = tid >> 4, cA = tid & 15;
  const short* Asrc = Ab + (size_t)(b * NN + i0 + rA) * NN + ((cA ^ (rA & 7)) * 8);
  const short* Hsrc[4];
#pragma unroll
  for (int p = 0; p < 4; ++p) {
    const int c = tid + 512 * p;
    const int f = c >> 4, ch = c & 15;
    Hsrc[p] = hT + (size_t)(b * NF + f) * NN + ((ch ^ (f & 7)) * 8);
  }

  // fragment ds_read offsets (swizzled); wave kg reads k-elems [kg*64, kg*64+64)
  int offA[2][2], offH[2][2];
#pragma unroll
  for (int mm = 0; mm < 2; ++mm)
#pragma unroll
    for (int ks = 0; ks < 2; ++ks) {
      const int r = 16 * mm + lo;
      const int ck = kg * 8 + ks * 4 + hi;
      offA[mm][ks] = r * 256 + ((ck ^ (r & 7)) << 4);
    }
#pragma unroll
  for (int nn = 0; nn < 2; ++nn)
#pragma unroll
    for (int ks = 0; ks < 2; ++ks) {
      const int f = 32 * wc + 16 * nn + lo;
      const int ck = kg * 8 + ks * 4 + hi;
      offH[nn][ks] = 8192 + f * 256 + ((ck ^ (f & 7)) << 4);
    }

  f32x4 acc[2][2] = {};

  // prologue: stage superstep 0 into buf0
  {
    char* nb = lds[0];
    gload_lds16(nb + tid * 16, Asrc);
#pragma unroll
    for (int p = 0; p < 4; ++p)
      gload_lds16(nb + 8192 + (tid + 512 * p) * 16, Hsrc[p]);
  }
  __syncthreads();

  const int NT = NN / 128;               // 16 supersteps
  for (int t = 0; t < NT; ++t) {
    if (t + 1 < NT) {
      char* nb = lds[(t + 1) & 1];
      const int koff = (t + 1) * 128;    // elements
      gload_lds16(nb + tid * 16, Asrc + koff);
#pragma unroll
      for (int p = 0; p < 4; ++p)
        gload_lds16(nb + 8192 + (tid + 512 * p) * 16, Hsrc[p] + koff);
    }
    const char* buf = lds[t & 1];
    bf16x8 af[2][2], hf[2][2];
#pragma unroll
    for (int mm = 0; mm < 2; ++mm)
#pragma unroll
      for (int ks = 0; ks < 2; ++ks)
        af[mm][ks] = *(const bf16x8*)(buf + offA[mm][ks]);
#pragma unroll
    for (int nn = 0; nn < 2; ++nn)
#pragma unroll
      for (int ks = 0; ks < 2; ++ks)
        hf[nn][ks] = *(const bf16x8*)(buf + offH[nn][ks]);
#pragma unroll
    for (int ks = 0; ks < 2; ++ks)
#pragma unroll
      for (int mm = 0; mm < 2; ++mm)
#pragma unroll
        for (int nn = 0; nn < 2; ++nn)
          acc[mm][nn] = __builtin_amdgcn_mfma_f32_16x16x32_bf16(
              af[mm][ks], hf[nn][ks], acc[mm][nn], 0, 0, 0);
    __syncthreads();                     // drains vmcnt -> next buf ready
  }

  // ---- exchange: sum K-half partials, split y into bf16 hi+lo ----
  float* yp = (float*)lds;               // [2][32][128] f32 = 32 KB
#pragma unroll
  for (int mm = 0; mm < 2; ++mm)
#pragma unroll
    for (int nn = 0; nn < 2; ++nn) {
      const int f = 32 * wc + 16 * nn + lo;
      const int ib = 16 * mm + hi * 4;
#pragma unroll
      for (int r = 0; r < 4; ++r)
        yp[kg * 4096 + (ib + r) * 128 + f] = acc[mm][nn][r];
    }
  __syncthreads();
  {
    const int ii = tid >> 4;             // 0..31
    const int fc = tid & 15;             // 16B chunk
    const float4 s0 = *(const float4*)(yp + ii * 128 + fc * 8);
    const float4 s1 = *(const float4*)(yp + ii * 128 + fc * 8 + 4);
    const float4 t0 = *(const float4*)(yp + 4096 + ii * 128 + fc * 8);
    const float4 t1 = *(const float4*)(yp + 4096 + ii * 128 + fc * 8 + 4);
    float v[8] = {s0.x + t0.x, s0.y + t0.y, s0.z + t0.z, s0.w + t0.w,
                  s1.x + t1.x, s1.y + t1.y, s1.z + t1.z, s1.w + t1.w};
    bf16x8 vh, vl;
#pragma unroll
    for (int q = 0; q < 8; ++q) {
      vh[q] = f2bf(v[q]);
      vl[q] = f2bf(v[q] - bf2f(vh[q]));
    }
    const int ch = fc ^ (ii & 7);
    *(bf16x8*)((char*)lds + 32768 + ii * 256 + ch * 16) = vh;
    *(bf16x8*)((char*)lds + 40960 + ii * 256 + ch * 16) = vl;
  }
  __syncthreads();

  // ---- stage 2: z = y @ W ; wave w owns o-cols [16w, 16w+16) ----
  f32x4 acc2[2] = {};
#pragma unroll
  for (int ks = 0; ks < 4; ++ks) {
#pragma unroll
    for (int mm = 0; mm < 2; ++mm) {
      const int r = 16 * mm + lo;
      const int ck = (ks * 4 + hi) ^ (r & 7);
      const bf16x8 ahi = *(const bf16x8*)((char*)lds + 32768 + r * 256 + (ck << 4));
      const bf16x8 alo = *(const bf16x8*)((char*)lds + 40960 + r * 256 + (ck << 4));
      acc2[mm] = __builtin_amdgcn_mfma_f32_16x16x32_bf16(ahi, wfrag[ks], acc2[mm], 0, 0, 0);
      acc2[mm] = __builtin_amdgcn_mfma_f32_16x16x32_bf16(alo, wfrag[ks], acc2[mm], 0, 0, 0);
    }
  }

  // ---- epilogue: z = dinv_i*acc2 + bias, relu?, + resid; write f32 (+ bf16^T) ----
  const int o = 16 * w + lo;
  const float bi = bias[o];
#pragma unroll
  for (int mm = 0; mm < 2; ++mm) {
    const int ib = i0 + 16 * mm + hi * 4;
    const float4 dv = *(const float4*)(dinv + b * NN + ib);
    const float dvr[4] = {dv.x, dv.y, dv.z, dv.w};
    float zr[4];
#pragma unroll
    for (int r = 0; r < 4; ++r) {
      float z = acc2[mm][r] * dvr[r] + bi;
      if (!LAST) z = fmaxf(z, 0.0f);
      const size_t idx = (size_t)(b * NN + ib + r) * NF + o;
      zr[r] = z + resid[idx];
      outF[idx] = zr[r];
    }
    if (!LAST) {
      short4v v;
#pragma unroll
      for (int r = 0; r < 4; ++r) v[r] = f2bf(zr[r] * dvr[r]);
      *(short4v*)(outT + (size_t)(b * NF + o) * NN + ib) = v;
    }
  }
}

extern "C" void kernel_launch(void* const* d_in, const int* in_sizes, int n_in,
                              void* d_out, int out_size, void* d_ws, size_t ws_size,
                              hipStream_t stream) {
  const float* x   = (const float*)d_in[0];
  const float* adj = (const float*)d_in[1];
  const float* W1  = (const float*)d_in[2];
  const float* b1  = (const float*)d_in[3];
  const float* W2  = (const float*)d_in[4];
  const float* b2  = (const float*)d_in[5];
  const float* W3  = (const float*)d_in[6];
  const float* b3  = (const float*)d_in[7];
  float* out = (float*)d_out;
  char* ws = (char*)d_ws;

  // workspace layout (bytes)
  float* dinv = (float*)(ws + 0);              // 32 KB
  short* wt   = (short*)(ws + 32768);          // 3 * 32 KB
  short* hT0  = (short*)(ws + 131072);         // 2 MB  (bf16 (x*dinv)^T)
  short* hT1  = (short*)(ws + 2228224);        // 2 MB
  short* hT2  = (short*)(ws + 4325376);        // 2 MB
  float* h1   = (float*)(ws + 6422528);        // 4 MB
  float* h2   = (float*)(ws + 10616832);       // 4 MB
  short* Ab   = (short*)(ws + 14811136);       // 32 MB (bf16 raw adj)

  k_prep<<<NB * NN, 256, 0, stream>>>(adj, dinv, Ab);
  k_misc<<<67, 256, 0, stream>>>(x, W1, W2, W3, dinv, hT0, wt);

  k_agg2<false><<<256, 512, 0, stream>>>(Ab, dinv, hT0, x,  wt,         b1, h1,  hT1);
  k_agg2<false><<<256, 512, 0, stream>>>(Ab, dinv, hT1, h1, wt + 16384, b2, h2,  hT2);
  k_agg2<true> <<<256, 512, 0, stream>>>(Ab, dinv, hT2, h2, wt + 32768, b3, out, nullptr);
}

// Round 5
// 64.626 us; speedup vs baseline: 5.7111x; 1.2456x over previous
//
#include <hip/hip_runtime.h>
#include <hip/hip_bf16.h>
#include <stdint.h>

#define NB 4
#define NN 2048
#define NF 128

typedef __attribute__((ext_vector_type(8))) short bf16x8;
typedef __attribute__((ext_vector_type(4))) short short4v;
typedef __attribute__((ext_vector_type(4))) float f32x4;

__device__ __forceinline__ short f2bf(float x) {
  __hip_bfloat16 h = __float2bfloat16(x);
  return *reinterpret_cast<short*>(&h);
}
__device__ __forceinline__ float bf2f(short s) {
  unsigned int u = ((unsigned int)(unsigned short)s) << 16;
  return __uint_as_float(u);
}

__device__ __forceinline__ void gload_lds16(void* lds, const void* g) {
  __builtin_amdgcn_global_load_lds(
      (const __attribute__((address_space(1))) unsigned int*)(uintptr_t)g,
      (__attribute__((address_space(3))) unsigned int*)(uintptr_t)lds,
      16, 0, 0);
}

// ---------------- Kernel 1: prep — row degree -> dinv, and Ab = bf16(adj) ----------------
__global__ __launch_bounds__(256) void k_prep(const float* __restrict__ adj,
                                              float* __restrict__ dinv,
                                              short* __restrict__ Ab) {
  const int row = blockIdx.x;          // 0 .. NB*NN-1
  const int tid = threadIdx.x;
  const float* src = adj + (size_t)row * NN + tid * 8;
  const float4 v0 = *(const float4*)(src);
  const float4 v1 = *(const float4*)(src + 4);
  bf16x8 o;
  o[0] = f2bf(v0.x); o[1] = f2bf(v0.y); o[2] = f2bf(v0.z); o[3] = f2bf(v0.w);
  o[4] = f2bf(v1.x); o[5] = f2bf(v1.y); o[6] = f2bf(v1.z); o[7] = f2bf(v1.w);
  *(bf16x8*)(Ab + (size_t)row * NN + tid * 8) = o;
  float s = v0.x + v0.y + v0.z + v0.w + v1.x + v1.y + v1.z + v1.w;
  s += __shfl_xor(s, 1);  s += __shfl_xor(s, 2);  s += __shfl_xor(s, 4);
  s += __shfl_xor(s, 8);  s += __shfl_xor(s, 16); s += __shfl_xor(s, 32);
  __shared__ float red[4];
  const int w = tid >> 6, lane = tid & 63;
  if (lane == 0) red[w] = s;
  __syncthreads();
  if (tid == 0) {
    const float d = red[0] + red[1] + red[2] + red[3];
    dinv[row] = rsqrtf(d + 1e-6f);
  }
}

// ---------------- Kernel 2: misc — hT0 = bf16((x*dinv_j)^T) (blocks 0..63), wt (64..66) ----
__global__ __launch_bounds__(256) void k_misc(const float* __restrict__ x,
                                              const float* __restrict__ W1,
                                              const float* __restrict__ W2,
                                              const float* __restrict__ W3,
                                              const float* __restrict__ dinv,
                                              short* __restrict__ xT,
                                              short* __restrict__ wt) {
  const int bid = blockIdx.x;
  const int tid = threadIdx.x;
  if (bid < 64) {
    const int b = bid >> 4;
    const int j0 = (bid & 15) << 7;
    __shared__ short tile[128 * 129];
#pragma unroll
    for (int r = 0; r < 8; ++r) {
      const int j = 16 * r + (tid >> 4);
      const int f0 = (tid & 15) * 8;
      const float sc = dinv[b * NN + j0 + j];
      const float4* p = (const float4*)(x + ((size_t)(b * NN + j0 + j)) * NF + f0);
      const float4 a0 = p[0], a1 = p[1];
      short* t = tile + j * 129 + f0;
      t[0] = f2bf(a0.x * sc); t[1] = f2bf(a0.y * sc);
      t[2] = f2bf(a0.z * sc); t[3] = f2bf(a0.w * sc);
      t[4] = f2bf(a1.x * sc); t[5] = f2bf(a1.y * sc);
      t[6] = f2bf(a1.z * sc); t[7] = f2bf(a1.w * sc);
    }
    __syncthreads();
#pragma unroll
    for (int r = 0; r < 8; ++r) {
      const int f = 16 * r + (tid >> 4);
      const int jc = tid & 15;
      bf16x8 v;
#pragma unroll
      for (int q = 0; q < 8; ++q) v[q] = tile[(jc * 8 + q) * 129 + f];
      *(bf16x8*)(xT + ((size_t)(b * NF + f)) * NN + j0 + jc * 8) = v;
    }
  } else {
    const int wl = bid - 64;
    const float* W = (wl == 0) ? W1 : (wl == 1) ? W2 : W3;
#pragma unroll 4
    for (int r = 0; r < 64; ++r) {
      const int e = r * 256 + tid;
      const int o = e >> 7, f = e & 127;
      wt[wl * 16384 + e] = f2bf(W[f * NF + o]);   // wt[o][f] = W[f][o]
    }
  }
}

// ---------------- Kernel 3: fused layer ----------------
// y = A_raw @ h_scaled  (BM=32, BN=128, BK=128, 8 waves: 4 col-slices x 2 K-halves)
// 3-buffer counted-vmcnt pipeline (T3+T4): tile t+1,t+2 stay in flight across
// barriers; never drain vmcnt to 0 in the main loop.
// then z = dinv_i*(y @ W) + bias (stage-2 MFMA, y split hi/lo bf16), relu?, + resid.
template <bool LAST>
__global__ __launch_bounds__(512) void k_agg2(const short* __restrict__ Ab,
                                              const float* __restrict__ dinv,
                                              const short* __restrict__ hT,
                                              const float* __restrict__ resid,
                                              const short* __restrict__ wT,
                                              const float* __restrict__ bias,
                                              float* __restrict__ outF,
                                              short* __restrict__ outT) {
  const int bid0 = blockIdx.x;
  const int bid = (bid0 & 7) * 32 + (bid0 >> 3);   // XCD-chunked swizzle (256 = 8*32)
  const int b = bid >> 6;
  const int i0 = (bid & 63) << 5;
  const int tid = threadIdx.x;
  const int w = tid >> 6, lane = tid & 63;
  const int lo = lane & 15, hi = lane >> 4;
  const int kg = w >> 2, wc = w & 3;

  __shared__ __align__(16) char lds[3][40960];   // per buf: A 32x128 (8K) + H 128x128 (32K)

  // stage-2 W fragments: B[k=f][n=o] from wT[o][f]
  bf16x8 wfrag[4];
#pragma unroll
  for (int ks = 0; ks < 4; ++ks)
    wfrag[ks] = *(const bf16x8*)(wT + (16 * w + lo) * NF + ks * 32 + hi * 8);
  // anchor: force wfrag loads to complete NOW so loop vmcnt bookkeeping is exact
  asm volatile("" :: "v"(wfrag[0]), "v"(wfrag[1]), "v"(wfrag[2]), "v"(wfrag[3]));

  // staging sources (pre-swizzled 16B chunk within each 256 B tile row)
  const int rA = tid >> 4, cA = tid & 15;
  const short* Asrc = Ab + (size_t)(b * NN + i0 + rA) * NN + ((cA ^ (rA & 7)) * 8);
  const short* Hsrc[4];
#pragma unroll
  for (int p = 0; p < 4; ++p) {
    const int c = tid + 512 * p;
    const int f = c >> 4, ch = c & 15;
    Hsrc[p] = hT + (size_t)(b * NF + f) * NN + ((ch ^ (f & 7)) * 8);
  }

  // fragment ds_read offsets (swizzled); wave kg reads k-elems [kg*64, kg*64+64)
  int offA[2][2], offH[2][2];
#pragma unroll
  for (int mm = 0; mm < 2; ++mm)
#pragma unroll
    for (int ks = 0; ks < 2; ++ks) {
      const int r = 16 * mm + lo;
      const int ck = kg * 8 + ks * 4 + hi;
      offA[mm][ks] = r * 256 + ((ck ^ (r & 7)) << 4);
    }
#pragma unroll
  for (int nn = 0; nn < 2; ++nn)
#pragma unroll
    for (int ks = 0; ks < 2; ++ks) {
      const int f = 32 * wc + 16 * nn + lo;
      const int ck = kg * 8 + ks * 4 + hi;
      offH[nn][ks] = 8192 + f * 256 + ((ck ^ (f & 7)) << 4);
    }

  f32x4 acc[2][2] = {};

#define STAGE_T(t_, base_)                                              \
  do {                                                                  \
    const int koff_ = (t_) * 128;                                       \
    char* nb_ = (base_);                                                \
    gload_lds16(nb_ + tid * 16, Asrc + koff_);                          \
    _Pragma("unroll")                                                   \
    for (int p_ = 0; p_ < 4; ++p_)                                      \
      gload_lds16(nb_ + 8192 + (tid + 512 * p_) * 16, Hsrc[p_] + koff_);\
  } while (0)

  // prologue: 2 tiles in flight (10 loads/thread)
  STAGE_T(0, lds[0]);
  STAGE_T(1, lds[1]);

  const int NT = NN / 128;               // 16 supersteps
  for (int t = 0; t < NT; ++t) {
    // wait for tile t (5 loads/thread of tile t+1 may remain in flight)
    if (t < NT - 1) asm volatile("s_waitcnt vmcnt(5)" ::: "memory");
    else            asm volatile("s_waitcnt vmcnt(0)" ::: "memory");
    asm volatile("s_barrier" ::: "memory");          // all waves' tile-t loads landed
    if (t + 2 < NT) STAGE_T(t + 2, lds[(t + 2) % 3]);  // overwrites t-1's buf (reads done)
    const char* buf = lds[t % 3];
    bf16x8 af[2][2], hf[2][2];
#pragma unroll
    for (int mm = 0; mm < 2; ++mm)
#pragma unroll
      for (int ks = 0; ks < 2; ++ks)
        af[mm][ks] = *(const bf16x8*)(buf + offA[mm][ks]);
#pragma unroll
    for (int nn = 0; nn < 2; ++nn)
#pragma unroll
      for (int ks = 0; ks < 2; ++ks)
        hf[nn][ks] = *(const bf16x8*)(buf + offH[nn][ks]);
#pragma unroll
    for (int ks = 0; ks < 2; ++ks)
#pragma unroll
      for (int mm = 0; mm < 2; ++mm)
#pragma unroll
        for (int nn = 0; nn < 2; ++nn)
          acc[mm][nn] = __builtin_amdgcn_mfma_f32_16x16x32_bf16(
              af[mm][ks], hf[nn][ks], acc[mm][nn], 0, 0, 0);
  }
#undef STAGE_T
  __syncthreads();                       // all tile-15 reads done before yp overwrite

  // ---- exchange: sum K-half partials, split y into bf16 hi+lo ----
  float* yp = (float*)lds;               // [2][32][128] f32 = 32 KB
#pragma unroll
  for (int mm = 0; mm < 2; ++mm)
#pragma unroll
    for (int nn = 0; nn < 2; ++nn) {
      const int f = 32 * wc + 16 * nn + lo;
      const int ib = 16 * mm + hi * 4;
#pragma unroll
      for (int r = 0; r < 4; ++r)
        yp[kg * 4096 + (ib + r) * 128 + f] = acc[mm][nn][r];
    }
  __syncthreads();
  {
    const int ii = tid >> 4;             // 0..31
    const int fc = tid & 15;             // 16B chunk
    const float4 s0 = *(const float4*)(yp + ii * 128 + fc * 8);
    const float4 s1 = *(const float4*)(yp + ii * 128 + fc * 8 + 4);
    const float4 t0 = *(const float4*)(yp + 4096 + ii * 128 + fc * 8);
    const float4 t1 = *(const float4*)(yp + 4096 + ii * 128 + fc * 8 + 4);
    float v[8] = {s0.x + t0.x, s0.y + t0.y, s0.z + t0.z, s0.w + t0.w,
                  s1.x + t1.x, s1.y + t1.y, s1.z + t1.z, s1.w + t1.w};
    bf16x8 vh, vl;
#pragma unroll
    for (int q = 0; q < 8; ++q) {
      vh[q] = f2bf(v[q]);
      vl[q] = f2bf(v[q] - bf2f(vh[q]));
    }
    const int ch = fc ^ (ii & 7);
    *(bf16x8*)((char*)lds + 32768 + ii * 256 + ch * 16) = vh;
    *(bf16x8*)((char*)lds + 40960 + ii * 256 + ch * 16) = vl;
  }
  __syncthreads();

  // ---- stage 2: z = y @ W ; wave w owns o-cols [16w, 16w+16) ----
  f32x4 acc2[2] = {};
#pragma unroll
  for (int ks = 0; ks < 4; ++ks) {
#pragma unroll
    for (int mm = 0; mm < 2; ++mm) {
      const int r = 16 * mm + lo;
      const int ck = (ks * 4 + hi) ^ (r & 7);
      const bf16x8 ahi = *(const bf16x8*)((char*)lds + 32768 + r * 256 + (ck << 4));
      const bf16x8 alo = *(const bf16x8*)((char*)lds + 40960 + r * 256 + (ck << 4));
      acc2[mm] = __builtin_amdgcn_mfma_f32_16x16x32_bf16(ahi, wfrag[ks], acc2[mm], 0, 0, 0);
      acc2[mm] = __builtin_amdgcn_mfma_f32_16x16x32_bf16(alo, wfrag[ks], acc2[mm], 0, 0, 0);
    }
  }

  // ---- epilogue: z = dinv_i*acc2 + bias, relu?, + resid; write f32 (+ bf16^T) ----
  const int o = 16 * w + lo;
  const float bi = bias[o];
#pragma unroll
  for (int mm = 0; mm < 2; ++mm) {
    const int ib = i0 + 16 * mm + hi * 4;
    const float4 dv = *(const float4*)(dinv + b * NN + ib);
    const float dvr[4] = {dv.x, dv.y, dv.z, dv.w};
    float zr[4];
#pragma unroll
    for (int r = 0; r < 4; ++r) {
      float z = acc2[mm][r] * dvr[r] + bi;
      if (!LAST) z = fmaxf(z, 0.0f);
      const size_t idx = (size_t)(b * NN + ib + r) * NF + o;
      zr[r] = z + resid[idx];
      outF[idx] = zr[r];
    }
    if (!LAST) {
      short4v v;
#pragma unroll
      for (int r = 0; r < 4; ++r) v[r] = f2bf(zr[r] * dvr[r]);
      *(short4v*)(outT + (size_t)(b * NF + o) * NN + ib) = v;
    }
  }
}

extern "C" void kernel_launch(void* const* d_in, const int* in_sizes, int n_in,
                              void* d_out, int out_size, void* d_ws, size_t ws_size,
                              hipStream_t stream) {
  const float* x   = (const float*)d_in[0];
  const float* adj = (const float*)d_in[1];
  const float* W1  = (const float*)d_in[2];
  const float* b1  = (const float*)d_in[3];
  const float* W2  = (const float*)d_in[4];
  const float* b2  = (const float*)d_in[5];
  const float* W3  = (const float*)d_in[6];
  const float* b3  = (const float*)d_in[7];
  float* out = (float*)d_out;
  char* ws = (char*)d_ws;

  // workspace layout (bytes)
  float* dinv = (float*)(ws + 0);              // 32 KB
  short* wt   = (short*)(ws + 32768);          // 3 * 32 KB
  short* hT0  = (short*)(ws + 131072);         // 2 MB  (bf16 (x*dinv)^T)
  short* hT1  = (short*)(ws + 2228224);        // 2 MB
  short* hT2  = (short*)(ws + 4325376);        // 2 MB
  float* h1   = (float*)(ws + 6422528);        // 4 MB
  float* h2   = (float*)(ws + 10616832);       // 4 MB
  short* Ab   = (short*)(ws + 14811136);       // 32 MB (bf16 raw adj)

  k_prep<<<NB * NN, 256, 0, stream>>>(adj, dinv, Ab);
  k_misc<<<67, 256, 0, stream>>>(x, W1, W2, W3, dinv, hT0, wt);

  k_agg2<false><<<256, 512, 0, stream>>>(Ab, dinv, hT0, x,  wt,         b1, h1,  hT1);
  k_agg2<false><<<256, 512, 0, stream>>>(Ab, dinv, hT1, h1, wt + 16384, b2, h2,  hT2);
  k_agg2<true> <<<256, 512, 0, stream>>>(Ab, dinv, hT2, h2, wt + 32768, b3, out, nullptr);
}